// Round 3
// baseline (430.466 us; speedup 1.0000x reference)
//
#include <hip/hip_runtime.h>

// ---------------------------------------------------------------------------
// GCN 3-layer forward, all f32. CSR-gather aggregation (no float atomics).
//
// Per call:
//   1. count in-degrees (int atomics) -> block-scan -> rowptr/cursor
//   2. counting-sort edges by dst -> perm_src (uint16, N<65536)
//   3. per-node insertion sort of neighbor lists by src  -> during the
//      aggregation all thread-groups sweep src in roughly the same order,
//      so each H row's ~deg reuses cluster in time and hit L2/L3.
//   4. layer 1: H1 = x@W1            ; AGG1 = Ahat(H1)
//      layer 2: H2 = relu(AGG1+b1)@W2; H3   = relu(Ahat(H2)+b2)
//      layer 3: T  = Ahat(H3)        ; out  = T@W3 + b3     [Ahat(HW)=(AhatH)W]
//   norm recomputed on the fly: norm(s,d) = dinv[s]*dinv[d].
// ---------------------------------------------------------------------------

#define DEV_INLINE __device__ __forceinline__

static DEV_INLINE void fma4(float4& acc, float a, const float4& w) {
    acc.x = fmaf(a, w.x, acc.x);
    acc.y = fmaf(a, w.y, acc.y);
    acc.z = fmaf(a, w.z, acc.z);
    acc.w = fmaf(a, w.w, acc.w);
}

// ------------------------------ CSR build -----------------------------------

__global__ void count_edges_kernel(int* __restrict__ cnt, const int* __restrict__ dst, int E) {
    int e = blockIdx.x * blockDim.x + threadIdx.x;
    if (e < E) atomicAdd(&cnt[dst[e]], 1);
}

// per-block exclusive scan of cnt -> rowptr(local); block totals -> bsum; dinv
__global__ void scan_block_kernel(const int* __restrict__ cnt, int* __restrict__ rowptr,
                                  int* __restrict__ bsum, float* __restrict__ dinv, int N) {
    __shared__ int buf[256];
    const int tid = threadIdx.x;
    const int i   = blockIdx.x * 256 + tid;
    int v = (i < N) ? cnt[i] : 0;
    if (i < N) dinv[i] = rsqrtf((float)(v + 1));   // +1 self-loop
    buf[tid] = v;
    __syncthreads();
#pragma unroll
    for (int ofs = 1; ofs < 256; ofs <<= 1) {
        int t = (tid >= ofs) ? buf[tid - ofs] : 0;
        __syncthreads();
        buf[tid] += t;
        __syncthreads();
    }
    if (i < N) rowptr[i] = buf[tid] - v;           // exclusive within block
    if (tid == 255) bsum[blockIdx.x] = buf[255];
}

// single-block exclusive scan of bsum (NB <= 256)
__global__ void scan_bsum_kernel(const int* __restrict__ bsum, int* __restrict__ bpref, int NB) {
    __shared__ int buf[256];
    const int tid = threadIdx.x;
    int v = (tid < NB) ? bsum[tid] : 0;
    buf[tid] = v;
    __syncthreads();
#pragma unroll
    for (int ofs = 1; ofs < 256; ofs <<= 1) {
        int t = (tid >= ofs) ? buf[tid - ofs] : 0;
        __syncthreads();
        buf[tid] += t;
        __syncthreads();
    }
    if (tid < NB) bpref[tid] = buf[tid] - v;
}

__global__ void finalize_rowptr_kernel(int* __restrict__ rowptr, int* __restrict__ cursor,
                                       const int* __restrict__ bpref, int N, int E) {
    int i = blockIdx.x * blockDim.x + threadIdx.x;
    if (i < N) {
        int r = rowptr[i] + bpref[i >> 8];
        rowptr[i] = r;
        cursor[i] = r;
    }
    if (i == 0) rowptr[N] = E;
}

__global__ void scatter_edges_kernel(const int* __restrict__ src, const int* __restrict__ dst,
                                     int* __restrict__ cursor,
                                     unsigned short* __restrict__ perm_src, int E) {
    int e = blockIdx.x * blockDim.x + threadIdx.x;
    if (e >= E) return;
    int d = dst[e];
    int pos = atomicAdd(&cursor[d], 1);
    perm_src[pos] = (unsigned short)src[e];
}

// per-node insertion sort of neighbor list by src (avg deg ~16, list L2-resident)
__global__ void sort_lists_kernel(const int* __restrict__ rowptr,
                                  unsigned short* __restrict__ perm, int N) {
    int i = blockIdx.x * blockDim.x + threadIdx.x;
    if (i >= N) return;
    int b = rowptr[i], e = rowptr[i + 1];
    for (int j = b + 1; j < e; ++j) {
        unsigned short key = perm[j];
        int k = j - 1;
        while (k >= b && perm[k] > key) { perm[k + 1] = perm[k]; --k; }
        perm[k + 1] = key;
    }
}

// --------------------------------- GEMM -------------------------------------
// C[N,NOUT] = preact(A[N,K]) @ W[K,NOUT] (+ bias if POSTB)
//   preact = PRE ? relu(a + bias[k]) : a
// block: 256 threads, BM=64 rows; K chunked at KC=64.

template<int K, int NOUT, bool PRE, bool POSTB>
__global__ __launch_bounds__(256, 2) void gemm_kernel(
    const float* __restrict__ A, const float* __restrict__ W,
    const float* __restrict__ bias, float* __restrict__ C, int N)
{
    constexpr int BM   = 64;
    constexpr int KC   = 64;
    constexpr int NCH  = K / KC;
    constexpr int COLT = NOUT / 8;
    constexpr int ROWT = 256 / COLT;
    constexpr int RPT  = BM / ROWT;
    constexpr int LDA  = KC + 4;

    __shared__ float  As[BM][LDA];
    __shared__ float4 Ws[KC][NOUT / 4];

    const int tid  = threadIdx.x;
    const int row0 = blockIdx.x * BM;
    const int tx   = tid % COLT;
    const int ty   = tid / COLT;

    float4 acc0[RPT], acc1[RPT];
#pragma unroll
    for (int i = 0; i < RPT; ++i) {
        acc0[i] = make_float4(0.f, 0.f, 0.f, 0.f);
        acc1[i] = make_float4(0.f, 0.f, 0.f, 0.f);
    }

    for (int ch = 0; ch < NCH; ++ch) {
        {
            const float4* Wg = reinterpret_cast<const float4*>(W + (size_t)ch * KC * NOUT);
            constexpr int TOT = KC * NOUT / 4;
            for (int idx = tid; idx < TOT; idx += 256)
                reinterpret_cast<float4*>(Ws)[idx] = Wg[idx];
        }
        {
            constexpr int KF  = KC / 4;
            constexpr int TOT = BM * KF;
            const float4* bias4 = reinterpret_cast<const float4*>(bias);
            for (int idx = tid; idx < TOT; idx += 256) {
                int r  = idx / KF;
                int kf = idx % KF;
                int gr = row0 + r;
                float4 v = make_float4(0.f, 0.f, 0.f, 0.f);
                if (gr < N) {
                    v = reinterpret_cast<const float4*>(A + (size_t)gr * K + ch * KC)[kf];
                    if (PRE) {
                        float4 b = bias4[ch * (KC / 4) + kf];
                        v.x = fmaxf(v.x + b.x, 0.f);
                        v.y = fmaxf(v.y + b.y, 0.f);
                        v.z = fmaxf(v.z + b.z, 0.f);
                        v.w = fmaxf(v.w + b.w, 0.f);
                    }
                }
                *reinterpret_cast<float4*>(&As[r][kf * 4]) = v;
            }
        }
        __syncthreads();

#pragma unroll 4
        for (int k = 0; k < KC; ++k) {
            float4 w0 = Ws[k][tx];
            float4 w1 = Ws[k][tx + NOUT / 8];
#pragma unroll
            for (int i = 0; i < RPT; ++i) {
                float a = As[ty + ROWT * i][k];
                fma4(acc0[i], a, w0);
                fma4(acc1[i], a, w1);
            }
        }
        __syncthreads();
    }

    if (POSTB) {
        const float4* bias4 = reinterpret_cast<const float4*>(bias);
        float4 pb0 = bias4[tx];
        float4 pb1 = bias4[tx + NOUT / 8];
#pragma unroll
        for (int i = 0; i < RPT; ++i) {
            acc0[i].x += pb0.x; acc0[i].y += pb0.y; acc0[i].z += pb0.z; acc0[i].w += pb0.w;
            acc1[i].x += pb1.x; acc1[i].y += pb1.y; acc1[i].z += pb1.z; acc1[i].w += pb1.w;
        }
    }

#pragma unroll
    for (int i = 0; i < RPT; ++i) {
        int gr = row0 + ty + ROWT * i;
        if (gr < N) {
            float4* C4 = reinterpret_cast<float4*>(C + (size_t)gr * NOUT);
            C4[tx]            = acc0[i];
            C4[tx + NOUT / 8] = acc1[i];
        }
    }
}

// ------------------------------ aggregation ---------------------------------
// OUT[i,:] = opt_relu( sum_{e in in(i)} H[src_e,:]*dinv[src_e]*dinv[i]
//                      + H[i,:]*dinv[i]^2 + opt_bias )
// GROUP = F/4 threads per node, float4 per lane. Lists sorted by src ->
// whole-GPU sweeps src in order, clustering row reuse for L2/L3.

template<int F, bool BIAS, bool RELU>
__global__ __launch_bounds__(256) void agg_gather_kernel(
    const float* __restrict__ H, const int* __restrict__ rowptr,
    const unsigned short* __restrict__ perm_src, const float* __restrict__ dinv,
    const float* __restrict__ bias, float* __restrict__ OUT, int N)
{
    constexpr int GROUP = F / 4;
    constexpr int NPB   = 256 / GROUP;
    const int lane = threadIdx.x % GROUP;
    const int g    = threadIdx.x / GROUP;
    const int node = blockIdx.x * NPB + g;
    if (node >= N) return;

    const int beg = rowptr[node];
    const int end = rowptr[node + 1];
    const float di = dinv[node];

    // self-loop term
    float4 h0 = reinterpret_cast<const float4*>(H + (size_t)node * F)[lane];
    float  ds = di * di;
    float4 acc  = make_float4(h0.x * ds, h0.y * ds, h0.z * ds, h0.w * ds);
    float4 acc2 = make_float4(0.f, 0.f, 0.f, 0.f);

    int e = beg;
    for (; e + 1 < end; e += 2) {
        int s0 = perm_src[e];
        int s1 = perm_src[e + 1];
        float n0 = dinv[s0] * di;
        float n1 = dinv[s1] * di;
        float4 a = reinterpret_cast<const float4*>(H + (size_t)s0 * F)[lane];
        float4 b = reinterpret_cast<const float4*>(H + (size_t)s1 * F)[lane];
        fma4(acc,  n0, a);
        fma4(acc2, n1, b);
    }
    if (e < end) {
        int s0 = perm_src[e];
        float n0 = dinv[s0] * di;
        float4 a = reinterpret_cast<const float4*>(H + (size_t)s0 * F)[lane];
        fma4(acc, n0, a);
    }
    acc.x += acc2.x; acc.y += acc2.y; acc.z += acc2.z; acc.w += acc2.w;

    if (BIAS) {
        float4 b = reinterpret_cast<const float4*>(bias)[lane];
        acc.x += b.x; acc.y += b.y; acc.z += b.z; acc.w += b.w;
    }
    if (RELU) {
        acc.x = fmaxf(acc.x, 0.f); acc.y = fmaxf(acc.y, 0.f);
        acc.z = fmaxf(acc.z, 0.f); acc.w = fmaxf(acc.w, 0.f);
    }
    reinterpret_cast<float4*>(OUT + (size_t)node * F)[lane] = acc;
}

// ------------------------------- launcher -----------------------------------

static inline size_t align_up(size_t v, size_t a) { return (v + a - 1) / a * a; }

extern "C" void kernel_launch(void* const* d_in, const int* in_sizes, int n_in,
                              void* d_out, int out_size, void* d_ws, size_t ws_size,
                              hipStream_t stream) {
    const float* x  = (const float*)d_in[0];
    const int*   ei = (const int*)d_in[1];
    const float* W1 = (const float*)d_in[2];
    const float* b1 = (const float*)d_in[3];
    const float* W2 = (const float*)d_in[4];
    const float* b2 = (const float*)d_in[5];
    const float* W3 = (const float*)d_in[6];
    const float* b3 = (const float*)d_in[7];
    float* out = (float*)d_out;

    const int N = in_sizes[0] / 128;   // 50000
    const int E = in_sizes[1] / 2;     // 800000
    const int* src = ei;
    const int* dst = ei + E;
    const int NB = (N + 255) / 256;    // scan blocks (196 <= 256)

    // workspace layout
    char* ws = (char*)d_ws;
    size_t off = 0;
    float* dinv   = (float*)(ws + off); off = align_up(off + (size_t)N * 4, 512);
    int*   rowptr = (int*)  (ws + off); off = align_up(off + (size_t)(N + 1) * 4, 512);
    int*   cursor = (int*)  (ws + off); off = align_up(off + (size_t)N * 4, 512);
    int*   bsum   = (int*)  (ws + off); off = align_up(off + (size_t)NB * 4, 512);
    int*   bpref  = (int*)  (ws + off); off = align_up(off + (size_t)NB * 4, 512);
    unsigned short* perm_src = (unsigned short*)(ws + off); off = align_up(off + (size_t)E * 2, 512);
    float* H      = (float*)(ws + off); off = align_up(off + (size_t)N * 128 * 4, 512);
    float* AGG    = (float*)(ws + off); off = align_up(off + (size_t)N * 128 * 4, 512);
    (void)ws_size;

    const int TPB = 256;
    dim3 blk(TPB);
    int gN   = (N + TPB - 1) / TPB;
    int gE   = (E + TPB - 1) / TPB;
    int gRow = (N + 63) / 64;

    // ---- CSR build (reused by all layers) ----
    hipMemsetAsync(cursor, 0, (size_t)N * 4, stream);
    count_edges_kernel<<<gE, blk, 0, stream>>>(cursor, dst, E);
    scan_block_kernel<<<NB, blk, 0, stream>>>(cursor, rowptr, bsum, dinv, N);
    scan_bsum_kernel<<<1, blk, 0, stream>>>(bsum, bpref, NB);
    finalize_rowptr_kernel<<<gN, blk, 0, stream>>>(rowptr, cursor, bpref, N, E);
    scatter_edges_kernel<<<gE, blk, 0, stream>>>(src, dst, cursor, perm_src, E);
    sort_lists_kernel<<<gN, blk, 0, stream>>>(rowptr, perm_src, N);

    // ---- layer 1: H1 = x@W1 ; AGG1 = Ahat(H1) ----
    gemm_kernel<128, 128, false, false><<<gRow, blk, 0, stream>>>(x, W1, nullptr, H, N);
    agg_gather_kernel<128, false, false><<<(N + 7) / 8, blk, 0, stream>>>(
        H, rowptr, perm_src, dinv, nullptr, AGG, N);

    // ---- layer 2: H2 = relu(AGG1+b1)@W2 ; H3 = relu(Ahat(H2)+b2) ----
    gemm_kernel<128, 64, true, false><<<gRow, blk, 0, stream>>>(AGG, W2, b1, H, N);
    agg_gather_kernel<64, true, true><<<(N + 15) / 16, blk, 0, stream>>>(
        H, rowptr, perm_src, dinv, b2, AGG, N);

    // ---- layer 3: T = Ahat(H3) ; out = T@W3 + b3 ----
    agg_gather_kernel<64, false, false><<<(N + 15) / 16, blk, 0, stream>>>(
        AGG, rowptr, perm_src, dinv, nullptr, H, N);
    gemm_kernel<64, 128, false, true><<<gRow, blk, 0, stream>>>(H, W3, b3, out, N);
}

// Round 4
// 312.126 us; speedup vs baseline: 1.3791x; 1.3791x over previous
//
#include <hip/hip_runtime.h>

// ---------------------------------------------------------------------------
// GCN 3-layer forward. CSR-gather aggregation, gather inputs packed bf16
// (f32 accumulation everywhere).
//
//   1. count in-degrees -> block-scan -> rowptr/cursor ; counting-sort by dst
//      -> perm_src (uint16, N<65536)
//   2. L1: H1bf = x@W1          ; AGG1f = Ahat(H1bf)
//      L2: H2bf = relu(AGG1f+b1)@W2 ; H3bf = relu(Ahat(H2bf)+b2)
//      L3: Tf   = Ahat(H3bf)    ; out = Tf@W3 + b3      [Ahat(HW)=(AhatH)W]
//   norm recomputed on the fly: norm(s,d) = dinv[s]*dinv[d].
//
// Rationale: gather L2-fill traffic floor = 8 XCDs x sizeof(H) (every XCD
// touches all rows of H); bf16 halves that floor. 3 bf16 roundings inject
// ~1e-3 absmax vs 5.5e-3 threshold.
// ---------------------------------------------------------------------------

#define DEV_INLINE __device__ __forceinline__

typedef unsigned int uint;

// ---- bf16 pack/unpack (RNE) ----
static DEV_INLINE uint f2bf(float f) {
    uint u = __float_as_uint(f);
    return (u + 0x7FFFu + ((u >> 16) & 1u)) >> 16;
}
static DEV_INLINE uint pack2(float a, float b) { return f2bf(a) | (f2bf(b) << 16); }
static DEV_INLINE float bflo(uint u) { return __uint_as_float(u << 16); }
static DEV_INLINE float bfhi(uint u) { return __uint_as_float(u & 0xFFFF0000u); }

static DEV_INLINE void fma4(float4& acc, float a, const float4& w) {
    acc.x = fmaf(a, w.x, acc.x);
    acc.y = fmaf(a, w.y, acc.y);
    acc.z = fmaf(a, w.z, acc.z);
    acc.w = fmaf(a, w.w, acc.w);
}

// 8 bf16 (uint4) * n -> two float4 accs
static DEV_INLINE void fma8(float4& a, float4& b, float n, const uint4& v) {
    a.x = fmaf(n, bflo(v.x), a.x); a.y = fmaf(n, bfhi(v.x), a.y);
    a.z = fmaf(n, bflo(v.y), a.z); a.w = fmaf(n, bfhi(v.y), a.w);
    b.x = fmaf(n, bflo(v.z), b.x); b.y = fmaf(n, bfhi(v.z), b.y);
    b.z = fmaf(n, bflo(v.w), b.z); b.w = fmaf(n, bfhi(v.w), b.w);
}

// ------------------------------ CSR build -----------------------------------

__global__ void count_edges_kernel(int* __restrict__ cnt, const int* __restrict__ dst, int E) {
    int e = blockIdx.x * blockDim.x + threadIdx.x;
    if (e < E) atomicAdd(&cnt[dst[e]], 1);
}

__global__ void scan_block_kernel(const int* __restrict__ cnt, int* __restrict__ rowptr,
                                  int* __restrict__ bsum, float* __restrict__ dinv, int N) {
    __shared__ int buf[256];
    const int tid = threadIdx.x;
    const int i   = blockIdx.x * 256 + tid;
    int v = (i < N) ? cnt[i] : 0;
    if (i < N) dinv[i] = rsqrtf((float)(v + 1));   // +1 self-loop
    buf[tid] = v;
    __syncthreads();
#pragma unroll
    for (int ofs = 1; ofs < 256; ofs <<= 1) {
        int t = (tid >= ofs) ? buf[tid - ofs] : 0;
        __syncthreads();
        buf[tid] += t;
        __syncthreads();
    }
    if (i < N) rowptr[i] = buf[tid] - v;
    if (tid == 255) bsum[blockIdx.x] = buf[255];
}

__global__ void scan_bsum_kernel(const int* __restrict__ bsum, int* __restrict__ bpref, int NB) {
    __shared__ int buf[256];
    const int tid = threadIdx.x;
    int v = (tid < NB) ? bsum[tid] : 0;
    buf[tid] = v;
    __syncthreads();
#pragma unroll
    for (int ofs = 1; ofs < 256; ofs <<= 1) {
        int t = (tid >= ofs) ? buf[tid - ofs] : 0;
        __syncthreads();
        buf[tid] += t;
        __syncthreads();
    }
    if (tid < NB) bpref[tid] = buf[tid] - v;
}

__global__ void finalize_rowptr_kernel(int* __restrict__ rowptr, int* __restrict__ cursor,
                                       const int* __restrict__ bpref, int N, int E) {
    int i = blockIdx.x * blockDim.x + threadIdx.x;
    if (i < N) {
        int r = rowptr[i] + bpref[i >> 8];
        rowptr[i] = r;
        cursor[i] = r;
    }
    if (i == 0) rowptr[N] = E;
}

__global__ void scatter_edges_kernel(const int* __restrict__ src, const int* __restrict__ dst,
                                     int* __restrict__ cursor,
                                     unsigned short* __restrict__ perm_src, int E) {
    int e = blockIdx.x * blockDim.x + threadIdx.x;
    if (e >= E) return;
    int d = dst[e];
    int pos = atomicAdd(&cursor[d], 1);
    perm_src[pos] = (unsigned short)src[e];
}

// --------------------------------- GEMM -------------------------------------
// C[N,NOUT] = preact(A[N,K]) @ W[K,NOUT] (+ bias if POSTB), A is f32.
//   preact = PRE ? relu(a + bias[k]) : a ; output f32 or packed bf16 (OUTBF).

template<int K, int NOUT, bool PRE, bool POSTB, bool OUTBF>
__global__ __launch_bounds__(256, 2) void gemm_kernel(
    const float* __restrict__ A, const float* __restrict__ W,
    const float* __restrict__ bias, void* __restrict__ C, int N)
{
    constexpr int BM   = 64;
    constexpr int KC   = 64;
    constexpr int NCH  = K / KC;
    constexpr int COLT = NOUT / 8;
    constexpr int ROWT = 256 / COLT;
    constexpr int RPT  = BM / ROWT;
    constexpr int LDA  = KC + 4;

    __shared__ float  As[BM][LDA];
    __shared__ float4 Ws[KC][NOUT / 4];

    const int tid  = threadIdx.x;
    const int row0 = blockIdx.x * BM;
    const int tx   = tid % COLT;
    const int ty   = tid / COLT;

    float4 acc0[RPT], acc1[RPT];
#pragma unroll
    for (int i = 0; i < RPT; ++i) {
        acc0[i] = make_float4(0.f, 0.f, 0.f, 0.f);
        acc1[i] = make_float4(0.f, 0.f, 0.f, 0.f);
    }

    for (int ch = 0; ch < NCH; ++ch) {
        {
            const float4* Wg = reinterpret_cast<const float4*>(W + (size_t)ch * KC * NOUT);
            constexpr int TOT = KC * NOUT / 4;
            for (int idx = tid; idx < TOT; idx += 256)
                reinterpret_cast<float4*>(Ws)[idx] = Wg[idx];
        }
        {
            constexpr int KF  = KC / 4;
            constexpr int TOT = BM * KF;
            const float4* bias4 = reinterpret_cast<const float4*>(bias);
            for (int idx = tid; idx < TOT; idx += 256) {
                int r  = idx / KF;
                int kf = idx % KF;
                int gr = row0 + r;
                float4 v = make_float4(0.f, 0.f, 0.f, 0.f);
                if (gr < N) {
                    v = reinterpret_cast<const float4*>(A + (size_t)gr * K + ch * KC)[kf];
                    if (PRE) {
                        float4 b = bias4[ch * (KC / 4) + kf];
                        v.x = fmaxf(v.x + b.x, 0.f);
                        v.y = fmaxf(v.y + b.y, 0.f);
                        v.z = fmaxf(v.z + b.z, 0.f);
                        v.w = fmaxf(v.w + b.w, 0.f);
                    }
                }
                *reinterpret_cast<float4*>(&As[r][kf * 4]) = v;
            }
        }
        __syncthreads();

#pragma unroll 4
        for (int k = 0; k < KC; ++k) {
            float4 w0 = Ws[k][tx];
            float4 w1 = Ws[k][tx + NOUT / 8];
#pragma unroll
            for (int i = 0; i < RPT; ++i) {
                float a = As[ty + ROWT * i][k];
                fma4(acc0[i], a, w0);
                fma4(acc1[i], a, w1);
            }
        }
        __syncthreads();
    }

    if (POSTB) {
        const float4* bias4 = reinterpret_cast<const float4*>(bias);
        float4 pb0 = bias4[tx];
        float4 pb1 = bias4[tx + NOUT / 8];
#pragma unroll
        for (int i = 0; i < RPT; ++i) {
            acc0[i].x += pb0.x; acc0[i].y += pb0.y; acc0[i].z += pb0.z; acc0[i].w += pb0.w;
            acc1[i].x += pb1.x; acc1[i].y += pb1.y; acc1[i].z += pb1.z; acc1[i].w += pb1.w;
        }
    }

#pragma unroll
    for (int i = 0; i < RPT; ++i) {
        int gr = row0 + ty + ROWT * i;
        if (gr < N) {
            if (OUTBF) {
                unsigned short* Cb = (unsigned short*)C + (size_t)gr * NOUT;
                uint2 u0, u1;
                u0.x = pack2(acc0[i].x, acc0[i].y); u0.y = pack2(acc0[i].z, acc0[i].w);
                u1.x = pack2(acc1[i].x, acc1[i].y); u1.y = pack2(acc1[i].z, acc1[i].w);
                *reinterpret_cast<uint2*>(Cb + tx * 4)            = u0;
                *reinterpret_cast<uint2*>(Cb + tx * 4 + NOUT / 2) = u1;
            } else {
                float4* C4 = reinterpret_cast<float4*>((float*)C + (size_t)gr * NOUT);
                C4[tx]            = acc0[i];
                C4[tx + NOUT / 8] = acc1[i];
            }
        }
    }
}

// ------------------------------ aggregation ---------------------------------
// OUT[i,:] = opt_relu( sum_{e in in(i)} Hbf[src_e,:]*dinv[src_e]*dinv[i]
//                      + Hbf[i,:]*dinv[i]^2 + opt_bias )
// H packed bf16 (uint = 2 elems). GROUP = F/8 lanes/node, 16B (uint4) per
// lane per row. 4-edge unroll, two acc sets for MLP. OUT f32 or bf16.

template<int F, bool BIAS, bool RELU, bool OUTBF>
__global__ __launch_bounds__(256) void agg_gather_kernel(
    const uint* __restrict__ H, const int* __restrict__ rowptr,
    const unsigned short* __restrict__ perm_src, const float* __restrict__ dinv,
    const float* __restrict__ bias, void* __restrict__ OUT, int N)
{
    constexpr int GROUP = F / 8;           // lanes per node
    constexpr int FW    = F / 2;           // uints per row
    constexpr int NPB   = 256 / GROUP;
    const int lane = threadIdx.x % GROUP;
    const int g    = threadIdx.x / GROUP;
    const int node = blockIdx.x * NPB + g;
    if (node >= N) return;

    const int beg = rowptr[node];
    const int end = rowptr[node + 1];
    const float di = dinv[node];

    // self-loop term
    float4 aA = make_float4(0.f, 0.f, 0.f, 0.f), aB = aA;   // set 0
    float4 bA = aA, bB = aA;                                // set 1
    {
        uint4 v = reinterpret_cast<const uint4*>(H + (size_t)node * FW)[lane];
        fma8(aA, aB, di * di, v);
    }

    int e = beg;
    for (; e + 3 < end; e += 4) {
        int s0 = perm_src[e];     int s1 = perm_src[e + 1];
        int s2 = perm_src[e + 2]; int s3 = perm_src[e + 3];
        float n0 = dinv[s0] * di, n1 = dinv[s1] * di;
        float n2 = dinv[s2] * di, n3 = dinv[s3] * di;
        uint4 v0 = reinterpret_cast<const uint4*>(H + (size_t)s0 * FW)[lane];
        uint4 v1 = reinterpret_cast<const uint4*>(H + (size_t)s1 * FW)[lane];
        uint4 v2 = reinterpret_cast<const uint4*>(H + (size_t)s2 * FW)[lane];
        uint4 v3 = reinterpret_cast<const uint4*>(H + (size_t)s3 * FW)[lane];
        fma8(aA, aB, n0, v0);
        fma8(bA, bB, n1, v1);
        fma8(aA, aB, n2, v2);
        fma8(bA, bB, n3, v3);
    }
    for (; e < end; ++e) {
        int s0 = perm_src[e];
        float n0 = dinv[s0] * di;
        uint4 v0 = reinterpret_cast<const uint4*>(H + (size_t)s0 * FW)[lane];
        fma8(aA, aB, n0, v0);
    }
    aA.x += bA.x; aA.y += bA.y; aA.z += bA.z; aA.w += bA.w;
    aB.x += bB.x; aB.y += bB.y; aB.z += bB.z; aB.w += bB.w;

    if (BIAS) {
        const float4* b4 = reinterpret_cast<const float4*>(bias);
        float4 c0 = b4[lane * 2], c1 = b4[lane * 2 + 1];
        aA.x += c0.x; aA.y += c0.y; aA.z += c0.z; aA.w += c0.w;
        aB.x += c1.x; aB.y += c1.y; aB.z += c1.z; aB.w += c1.w;
    }
    if (RELU) {
        aA.x = fmaxf(aA.x, 0.f); aA.y = fmaxf(aA.y, 0.f);
        aA.z = fmaxf(aA.z, 0.f); aA.w = fmaxf(aA.w, 0.f);
        aB.x = fmaxf(aB.x, 0.f); aB.y = fmaxf(aB.y, 0.f);
        aB.z = fmaxf(aB.z, 0.f); aB.w = fmaxf(aB.w, 0.f);
    }

    if (OUTBF) {
        uint4 u;
        u.x = pack2(aA.x, aA.y); u.y = pack2(aA.z, aA.w);
        u.z = pack2(aB.x, aB.y); u.w = pack2(aB.z, aB.w);
        reinterpret_cast<uint4*>((uint*)OUT + (size_t)node * FW)[lane] = u;
    } else {
        float4* O = reinterpret_cast<float4*>((float*)OUT + (size_t)node * F);
        O[lane * 2]     = aA;
        O[lane * 2 + 1] = aB;
    }
}

// ------------------------------- launcher -----------------------------------

static inline size_t align_up(size_t v, size_t a) { return (v + a - 1) / a * a; }

extern "C" void kernel_launch(void* const* d_in, const int* in_sizes, int n_in,
                              void* d_out, int out_size, void* d_ws, size_t ws_size,
                              hipStream_t stream) {
    const float* x  = (const float*)d_in[0];
    const int*   ei = (const int*)d_in[1];
    const float* W1 = (const float*)d_in[2];
    const float* b1 = (const float*)d_in[3];
    const float* W2 = (const float*)d_in[4];
    const float* b2 = (const float*)d_in[5];
    const float* W3 = (const float*)d_in[6];
    const float* b3 = (const float*)d_in[7];
    float* out = (float*)d_out;

    const int N = in_sizes[0] / 128;   // 50000
    const int E = in_sizes[1] / 2;     // 800000
    const int* src = ei;
    const int* dst = ei + E;
    const int NB = (N + 255) / 256;

    // workspace layout
    char* ws = (char*)d_ws;
    size_t off = 0;
    float* dinv   = (float*)(ws + off); off = align_up(off + (size_t)N * 4, 512);
    int*   rowptr = (int*)  (ws + off); off = align_up(off + (size_t)(N + 1) * 4, 512);
    int*   cursor = (int*)  (ws + off); off = align_up(off + (size_t)N * 4, 512);
    int*   bsum   = (int*)  (ws + off); off = align_up(off + (size_t)NB * 4, 512);
    int*   bpref  = (int*)  (ws + off); off = align_up(off + (size_t)NB * 4, 512);
    unsigned short* perm_src = (unsigned short*)(ws + off); off = align_up(off + (size_t)E * 2, 512);
    uint*  Hbf    = (uint*) (ws + off); off = align_up(off + (size_t)N * 128 * 2, 512);  // bf16 area
    float* Af32   = (float*)(ws + off); off = align_up(off + (size_t)N * 128 * 4, 512);  // f32 area
    (void)ws_size;

    // bf16 area sub-use: L1: H1bf = full N*64 uints; L2: H2bf = first N*32,
    // H3bf (=relu(agg2)) = second N*32.
    uint* H1bf = Hbf;
    uint* H2bf = Hbf;
    uint* H3bf = Hbf + (size_t)N * 32;
    // f32 area sub-use: AGG1 (N*128), later T (N*64).
    float* AGG1 = Af32;
    float* T    = Af32;

    const int TPB = 256;
    dim3 blk(TPB);
    int gN   = (N + TPB - 1) / TPB;
    int gE   = (E + TPB - 1) / TPB;
    int gRow = (N + 63) / 64;

    // ---- CSR build (reused by all layers) ----
    hipMemsetAsync(cursor, 0, (size_t)N * 4, stream);
    count_edges_kernel<<<gE, blk, 0, stream>>>(cursor, dst, E);
    scan_block_kernel<<<NB, blk, 0, stream>>>(cursor, rowptr, bsum, dinv, N);
    scan_bsum_kernel<<<1, blk, 0, stream>>>(bsum, bpref, NB);
    finalize_rowptr_kernel<<<gN, blk, 0, stream>>>(rowptr, cursor, bpref, N, E);
    scatter_edges_kernel<<<gE, blk, 0, stream>>>(src, dst, cursor, perm_src, E);

    // ---- layer 1: H1bf = x@W1 ; AGG1 = Ahat(H1bf) ----
    gemm_kernel<128, 128, false, false, true><<<gRow, blk, 0, stream>>>(x, W1, nullptr, H1bf, N);
    agg_gather_kernel<128, false, false, false><<<(N + 15) / 16, blk, 0, stream>>>(
        H1bf, rowptr, perm_src, dinv, nullptr, AGG1, N);

    // ---- layer 2: H2bf = relu(AGG1+b1)@W2 ; H3bf = relu(Ahat(H2bf)+b2) ----
    gemm_kernel<128, 64, true, false, true><<<gRow, blk, 0, stream>>>(AGG1, W2, b1, H2bf, N);
    agg_gather_kernel<64, true, true, true><<<(N + 31) / 32, blk, 0, stream>>>(
        H2bf, rowptr, perm_src, dinv, b2, H3bf, N);

    // ---- layer 3: T = Ahat(H3bf) ; out = T@W3 + b3 ----
    agg_gather_kernel<64, false, false, false><<<(N + 31) / 32, blk, 0, stream>>>(
        H3bf, rowptr, perm_src, dinv, nullptr, T, N);
    gemm_kernel<64, 128, false, true, false><<<gRow, blk, 0, stream>>>(T, W3, b3, out, N);
}

// Round 5
// 306.989 us; speedup vs baseline: 1.4022x; 1.0167x over previous
//
#include <hip/hip_runtime.h>

// ---------------------------------------------------------------------------
// GCN 3-layer forward. CSR-gather aggregation (bf16 H, f32 accum) +
// MFMA GEMMs via bf16 hi/lo split (3-product f32 emulation).
//
//   CSR: count -> scan -> windowed 8-pass counting-sort by dst (perm uint16)
//   L1: H1bf = x@W1              ; AGG1f = Ahat(H1bf)
//   L2: H2bf = relu(AGG1f+b1)@W2 ; H3bf  = relu(Ahat(H2bf)+b2)
//   L3: Tf   = Ahat(H3bf)        ; out   = Tf@W3 + b3    [Ahat(HW)=(AhatH)W]
//
// GEMM: A split A=Ah+Al (bf16 truncation), W pre-split into fragment-ordered
// bf16 arrays (prep kernel). D ~= AhWh + AhWl + AlWh; dropped AlBl ~2^-16 rel.
// MFMA 16x16x32 bf16; A[row=l&15][k=(l>>4)*8+j], B[k=(l>>4)*8+j][col=l&15],
// C/D col=l&15,row=(l>>4)*4+r (learn_hip m89).
// ---------------------------------------------------------------------------

#define DEV_INLINE __device__ __forceinline__

typedef unsigned int uint;
typedef unsigned short ushort;
typedef __attribute__((ext_vector_type(8))) short bf16x8;
typedef __attribute__((ext_vector_type(4))) float f32x4;

// ---- bf16 helpers ----
static DEV_INLINE uint f2bf_rne(float f) {               // round-nearest-even
    uint u = __float_as_uint(f);
    return (u + 0x7FFFu + ((u >> 16) & 1u)) >> 16;
}
static DEV_INLINE uint pack2(float a, float b) { return f2bf_rne(a) | (f2bf_rne(b) << 16); }
static DEV_INLINE float bflo(uint u) { return __uint_as_float(u << 16); }
static DEV_INLINE float bfhi(uint u) { return __uint_as_float(u & 0xFFFF0000u); }

static DEV_INLINE void fma8(float4& a, float4& b, float n, const uint4& v) {
    a.x = fmaf(n, bflo(v.x), a.x); a.y = fmaf(n, bfhi(v.x), a.y);
    a.z = fmaf(n, bflo(v.y), a.z); a.w = fmaf(n, bfhi(v.y), a.w);
    b.x = fmaf(n, bflo(v.z), b.x); b.y = fmaf(n, bfhi(v.z), b.y);
    b.z = fmaf(n, bflo(v.w), b.z); b.w = fmaf(n, bfhi(v.w), b.w);
}

// hi/lo truncation split of 8 f32 -> two bf16x8
static DEV_INLINE void split8(const float4& x0, const float4& x1, bf16x8& ah, bf16x8& al) {
    float xs[8] = {x0.x, x0.y, x0.z, x0.w, x1.x, x1.y, x1.z, x1.w};
#pragma unroll
    for (int j = 0; j < 8; ++j) {
        uint u = __float_as_uint(xs[j]);
        ah[j] = (short)(u >> 16);
        float r = xs[j] - __uint_as_float(u & 0xFFFF0000u);
        al[j] = (short)(__float_as_uint(r) >> 16);
    }
}

// ------------------------------ CSR build -----------------------------------

__global__ void count_edges_kernel(int* __restrict__ cnt, const int* __restrict__ dst, int E) {
    int e = blockIdx.x * blockDim.x + threadIdx.x;
    if (e < E) atomicAdd(&cnt[dst[e]], 1);
}

__global__ void scan_block_kernel(const int* __restrict__ cnt, int* __restrict__ rowptr,
                                  int* __restrict__ bsum, float* __restrict__ dinv, int N) {
    __shared__ int buf[256];
    const int tid = threadIdx.x;
    const int i   = blockIdx.x * 256 + tid;
    int v = (i < N) ? cnt[i] : 0;
    if (i < N) dinv[i] = rsqrtf((float)(v + 1));   // +1 self-loop
    buf[tid] = v;
    __syncthreads();
#pragma unroll
    for (int ofs = 1; ofs < 256; ofs <<= 1) {
        int t = (tid >= ofs) ? buf[tid - ofs] : 0;
        __syncthreads();
        buf[tid] += t;
        __syncthreads();
    }
    if (i < N) rowptr[i] = buf[tid] - v;
    if (tid == 255) bsum[blockIdx.x] = buf[255];
}

__global__ void scan_bsum_kernel(const int* __restrict__ bsum, int* __restrict__ bpref, int NB) {
    __shared__ int buf[256];
    const int tid = threadIdx.x;
    int v = (tid < NB) ? bsum[tid] : 0;
    buf[tid] = v;
    __syncthreads();
#pragma unroll
    for (int ofs = 1; ofs < 256; ofs <<= 1) {
        int t = (tid >= ofs) ? buf[tid - ofs] : 0;
        __syncthreads();
        buf[tid] += t;
        __syncthreads();
    }
    if (tid < NB) bpref[tid] = buf[tid] - v;
}

__global__ void finalize_rowptr_kernel(int* __restrict__ rowptr, int* __restrict__ cursor,
                                       const int* __restrict__ bpref, int N, int E) {
    int i = blockIdx.x * blockDim.x + threadIdx.x;
    if (i < N) {
        int r = rowptr[i] + bpref[i >> 8];
        rowptr[i] = r;
        cursor[i] = r;
    }
    if (i == 0) rowptr[N] = E;
}

// windowed scatter: only edges with dst in [lo,hi) -> perm/cursor writes stay
// in an L2-resident window (kills dirty-line write amplification)
__global__ void scatter_edges_pass_kernel(const int* __restrict__ src, const int* __restrict__ dst,
                                          int* __restrict__ cursor,
                                          ushort* __restrict__ perm_src, int E, int lo, int hi) {
    int e = blockIdx.x * blockDim.x + threadIdx.x;
    if (e >= E) return;
    int d = dst[e];
    if (d < lo || d >= hi) return;
    int pos = atomicAdd(&cursor[d], 1);
    perm_src[pos] = (ushort)src[e];
}

// ------------------------- W fragment prep (bf16 split) ---------------------
// For each (t,c,lane,j): frag[( (t*C+c)*64 + lane )*8 + j] =
//   split of W[t*32 + (lane>>4)*8 + j][c*16 + (lane&15)]

template<int K, int NOUT>
__global__ void prep_wfrag_kernel(const float* __restrict__ W,
                                  ushort* __restrict__ Wh, ushort* __restrict__ Wl) {
    constexpr int C = NOUT / 16;
    constexpr int TOT = (K / 32) * C * 64;
    int id = blockIdx.x * blockDim.x + threadIdx.x;
    if (id >= TOT) return;
    int lane = id & 63;
    int tc   = id >> 6;
    int c = tc % C, t = tc / C;
    int krow = t * 32 + (lane >> 4) * 8;
    int col  = c * 16 + (lane & 15);
    ushort h[8], l[8];
#pragma unroll
    for (int j = 0; j < 8; ++j) {
        float w = W[(size_t)(krow + j) * NOUT + col];
        uint u = __float_as_uint(w);
        h[j] = (ushort)(u >> 16);
        float r = w - __uint_as_float(u & 0xFFFF0000u);
        l[j] = (ushort)(__float_as_uint(r) >> 16);
    }
#pragma unroll
    for (int j = 0; j < 8; ++j) { Wh[(size_t)id * 8 + j] = h[j]; Wl[(size_t)id * 8 + j] = l[j]; }
}

// ------------------------------ MFMA GEMM -----------------------------------
// C[N,NOUT] = preact(A[N,K]) @ W ; preact = PRE ? relu(a+bias_k[k]) : a
// OUTBF: pack output to bf16 ; POSTB: add bias_n[col] (f32 out only)
// 4 waves/block, wave = 16 rows; no LDS; W frags from L2.

template<int K, int NOUT, bool PRE, bool POSTB, bool OUTBF>
__global__ __launch_bounds__(256) void gemm_mfma_kernel(
    const float* __restrict__ A, const ushort* __restrict__ Whf, const ushort* __restrict__ Wlf,
    const float* __restrict__ bias_k, const float* __restrict__ bias_n,
    void* __restrict__ Cout, int N)
{
    constexpr int C  = NOUT / 16;   // col tiles
    constexpr int T  = K / 32;      // k steps
    const int tid  = threadIdx.x;
    const int w    = tid >> 6;
    const int lane = tid & 63;
    const int row0 = blockIdx.x * 64 + w * 16;

    const int arow  = row0 + (lane & 15);
    const int arowc = (arow < N) ? arow : (N - 1);      // clamped for loads
    const int lq    = (lane >> 4);                       // k-chunk 0..3

    const bf16x8* WH = reinterpret_cast<const bf16x8*>(Whf);
    const bf16x8* WL = reinterpret_cast<const bf16x8*>(Wlf);

    f32x4 acc[C];
#pragma unroll
    for (int c = 0; c < C; ++c) acc[c] = (f32x4){0.f, 0.f, 0.f, 0.f};

#pragma unroll
    for (int t = 0; t < T; ++t) {
        const float* ap = A + (size_t)arowc * K + t * 32 + lq * 8;
        float4 x0 = *reinterpret_cast<const float4*>(ap);
        float4 x1 = *reinterpret_cast<const float4*>(ap + 4);
        if (PRE) {
            const float* bp = bias_k + t * 32 + lq * 8;
            float4 b0 = *reinterpret_cast<const float4*>(bp);
            float4 b1 = *reinterpret_cast<const float4*>(bp + 4);
            x0.x = fmaxf(x0.x + b0.x, 0.f); x0.y = fmaxf(x0.y + b0.y, 0.f);
            x0.z = fmaxf(x0.z + b0.z, 0.f); x0.w = fmaxf(x0.w + b0.w, 0.f);
            x1.x = fmaxf(x1.x + b1.x, 0.f); x1.y = fmaxf(x1.y + b1.y, 0.f);
            x1.z = fmaxf(x1.z + b1.z, 0.f); x1.w = fmaxf(x1.w + b1.w, 0.f);
        }
        bf16x8 ah, al;
        split8(x0, x1, ah, al);
#pragma unroll
        for (int c = 0; c < C; ++c) {
            bf16x8 bh = WH[(t * C + c) * 64 + lane];
            bf16x8 bl = WL[(t * C + c) * 64 + lane];
            acc[c] = __builtin_amdgcn_mfma_f32_16x16x32_bf16(ah, bh, acc[c], 0, 0, 0);
            acc[c] = __builtin_amdgcn_mfma_f32_16x16x32_bf16(al, bh, acc[c], 0, 0, 0);
            acc[c] = __builtin_amdgcn_mfma_f32_16x16x32_bf16(ah, bl, acc[c], 0, 0, 0);
        }
    }

    // epilogue: lane holds C/D row=(lane>>4)*4+r, col=c*16+(lane&15)
    const int rbase = (lane >> 4) * 4;
    const int ccol  = (lane & 15);
#pragma unroll
    for (int c = 0; c < C; ++c) {
        int col = c * 16 + ccol;
        float pb = POSTB ? bias_n[col] : 0.f;
#pragma unroll
        for (int r = 0; r < 4; ++r) {
            int row = row0 + rbase + r;
            if (row < N) {
                float v = acc[c][r] + pb;
                if (OUTBF) ((ushort*)Cout)[(size_t)row * NOUT + col] = (ushort)f2bf_rne(v);
                else       ((float*)Cout)[(size_t)row * NOUT + col] = v;
            }
        }
    }
}

// ------------------------------ aggregation ---------------------------------
// OUT[i,:] = opt_relu( sum_e Hbf[src_e,:]*dinv[src_e]*dinv[i]
//                      + Hbf[i,:]*dinv[i]^2 + opt_bias )

template<int F, bool BIAS, bool RELU, bool OUTBF>
__global__ __launch_bounds__(256) void agg_gather_kernel(
    const uint* __restrict__ H, const int* __restrict__ rowptr,
    const ushort* __restrict__ perm_src, const float* __restrict__ dinv,
    const float* __restrict__ bias, void* __restrict__ OUT, int N)
{
    constexpr int GROUP = F / 8;
    constexpr int FW    = F / 2;
    constexpr int NPB   = 256 / GROUP;
    const int lane = threadIdx.x % GROUP;
    const int g    = threadIdx.x / GROUP;
    const int node = blockIdx.x * NPB + g;
    if (node >= N) return;

    const int beg = rowptr[node];
    const int end = rowptr[node + 1];
    const float di = dinv[node];

    float4 aA = make_float4(0.f, 0.f, 0.f, 0.f), aB = aA;
    float4 bA = aA, bB = aA;
    {
        uint4 v = reinterpret_cast<const uint4*>(H + (size_t)node * FW)[lane];
        fma8(aA, aB, di * di, v);
    }

    int e = beg;
    for (; e + 3 < end; e += 4) {
        int s0 = perm_src[e];     int s1 = perm_src[e + 1];
        int s2 = perm_src[e + 2]; int s3 = perm_src[e + 3];
        float n0 = dinv[s0] * di, n1 = dinv[s1] * di;
        float n2 = dinv[s2] * di, n3 = dinv[s3] * di;
        uint4 v0 = reinterpret_cast<const uint4*>(H + (size_t)s0 * FW)[lane];
        uint4 v1 = reinterpret_cast<const uint4*>(H + (size_t)s1 * FW)[lane];
        uint4 v2 = reinterpret_cast<const uint4*>(H + (size_t)s2 * FW)[lane];
        uint4 v3 = reinterpret_cast<const uint4*>(H + (size_t)s3 * FW)[lane];
        fma8(aA, aB, n0, v0);
        fma8(bA, bB, n1, v1);
        fma8(aA, aB, n2, v2);
        fma8(bA, bB, n3, v3);
    }
    for (; e < end; ++e) {
        int s0 = perm_src[e];
        float n0 = dinv[s0] * di;
        uint4 v0 = reinterpret_cast<const uint4*>(H + (size_t)s0 * FW)[lane];
        fma8(aA, aB, n0, v0);
    }
    aA.x += bA.x; aA.y += bA.y; aA.z += bA.z; aA.w += bA.w;
    aB.x += bB.x; aB.y += bB.y; aB.z += bB.z; aB.w += bB.w;

    if (BIAS) {
        const float4* b4 = reinterpret_cast<const float4*>(bias);
        float4 c0 = b4[lane * 2], c1 = b4[lane * 2 + 1];
        aA.x += c0.x; aA.y += c0.y; aA.z += c0.z; aA.w += c0.w;
        aB.x += c1.x; aB.y += c1.y; aB.z += c1.z; aB.w += c1.w;
    }
    if (RELU) {
        aA.x = fmaxf(aA.x, 0.f); aA.y = fmaxf(aA.y, 0.f);
        aA.z = fmaxf(aA.z, 0.f); aA.w = fmaxf(aA.w, 0.f);
        aB.x = fmaxf(aB.x, 0.f); aB.y = fmaxf(aB.y, 0.f);
        aB.z = fmaxf(aB.z, 0.f); aB.w = fmaxf(aB.w, 0.f);
    }

    if (OUTBF) {
        uint4 u;
        u.x = pack2(aA.x, aA.y); u.y = pack2(aA.z, aA.w);
        u.z = pack2(aB.x, aB.y); u.w = pack2(aB.z, aB.w);
        reinterpret_cast<uint4*>((uint*)OUT + (size_t)node * FW)[lane] = u;
    } else {
        float4* O = reinterpret_cast<float4*>((float*)OUT + (size_t)node * F);
        O[lane * 2]     = aA;
        O[lane * 2 + 1] = aB;
    }
}

// ------------------------------- launcher -----------------------------------

static inline size_t align_up(size_t v, size_t a) { return (v + a - 1) / a * a; }

extern "C" void kernel_launch(void* const* d_in, const int* in_sizes, int n_in,
                              void* d_out, int out_size, void* d_ws, size_t ws_size,
                              hipStream_t stream) {
    const float* x  = (const float*)d_in[0];
    const int*   ei = (const int*)d_in[1];
    const float* W1 = (const float*)d_in[2];
    const float* b1 = (const float*)d_in[3];
    const float* W2 = (const float*)d_in[4];
    const float* b2 = (const float*)d_in[5];
    const float* W3 = (const float*)d_in[6];
    const float* b3 = (const float*)d_in[7];
    float* out = (float*)d_out;

    const int N = in_sizes[0] / 128;   // 50000
    const int E = in_sizes[1] / 2;     // 800000
    const int* src = ei;
    const int* dst = ei + E;
    const int NB = (N + 255) / 256;

    // workspace layout
    char* ws = (char*)d_ws;
    size_t off = 0;
    float* dinv   = (float*)(ws + off); off = align_up(off + (size_t)N * 4, 512);
    int*   rowptr = (int*)  (ws + off); off = align_up(off + (size_t)(N + 1) * 4, 512);
    int*   cursor = (int*)  (ws + off); off = align_up(off + (size_t)N * 4, 512);
    int*   bsum   = (int*)  (ws + off); off = align_up(off + (size_t)NB * 4, 512);
    int*   bpref  = (int*)  (ws + off); off = align_up(off + (size_t)NB * 4, 512);
    ushort* perm_src = (ushort*)(ws + off); off = align_up(off + (size_t)E * 2, 512);
    uint*  Hbf    = (uint*) (ws + off); off = align_up(off + (size_t)N * 128 * 2, 512);
    float* Af32   = (float*)(ws + off); off = align_up(off + (size_t)N * 128 * 4, 512);
    ushort* w1h   = (ushort*)(ws + off); off = align_up(off + (size_t)128 * 128 * 2, 512);
    ushort* w1l   = (ushort*)(ws + off); off = align_up(off + (size_t)128 * 128 * 2, 512);
    ushort* w2h   = (ushort*)(ws + off); off = align_up(off + (size_t)128 * 64 * 2, 512);
    ushort* w2l   = (ushort*)(ws + off); off = align_up(off + (size_t)128 * 64 * 2, 512);
    ushort* w3h   = (ushort*)(ws + off); off = align_up(off + (size_t)64 * 128 * 2, 512);
    ushort* w3l   = (ushort*)(ws + off); off = align_up(off + (size_t)64 * 128 * 2, 512);
    (void)ws_size;

    uint* H1bf = Hbf;
    uint* H2bf = Hbf;
    uint* H3bf = Hbf + (size_t)N * 32;
    float* AGG1 = Af32;
    float* T    = Af32;

    const int TPB = 256;
    dim3 blk(TPB);
    int gN   = (N + TPB - 1) / TPB;
    int gE   = (E + TPB - 1) / TPB;
    int gRow = (N + 63) / 64;

    // ---- W fragment prep (tiny) ----
    prep_wfrag_kernel<128, 128><<<(4 * 8 * 64 + 255) / 256, blk, 0, stream>>>(W1, w1h, w1l);
    prep_wfrag_kernel<128, 64><<<(4 * 4 * 64 + 255) / 256, blk, 0, stream>>>(W2, w2h, w2l);
    prep_wfrag_kernel<64, 128><<<(2 * 8 * 64 + 255) / 256, blk, 0, stream>>>(W3, w3h, w3l);

    // ---- CSR build ----
    hipMemsetAsync(cursor, 0, (size_t)N * 4, stream);
    count_edges_kernel<<<gE, blk, 0, stream>>>(cursor, dst, E);
    scan_block_kernel<<<NB, blk, 0, stream>>>(cursor, rowptr, bsum, dinv, N);
    scan_bsum_kernel<<<1, blk, 0, stream>>>(bsum, bpref, NB);
    finalize_rowptr_kernel<<<gN, blk, 0, stream>>>(rowptr, cursor, bpref, N, E);
    {
        const int NPASS = 8;
        int win = (N + NPASS - 1) / NPASS;
        for (int p = 0; p < NPASS; ++p) {
            int lo = p * win;
            int hi = (lo + win < N) ? lo + win : N;
            scatter_edges_pass_kernel<<<gE, blk, 0, stream>>>(src, dst, cursor, perm_src, E, lo, hi);
        }
    }

    // ---- layer 1 ----
    gemm_mfma_kernel<128, 128, false, false, true><<<gRow, blk, 0, stream>>>(
        x, w1h, w1l, nullptr, nullptr, H1bf, N);
    agg_gather_kernel<128, false, false, false><<<(N + 15) / 16, blk, 0, stream>>>(
        H1bf, rowptr, perm_src, dinv, nullptr, AGG1, N);

    // ---- layer 2 ----
    gemm_mfma_kernel<128, 64, true, false, true><<<gRow, blk, 0, stream>>>(
        AGG1, w2h, w2l, b1, nullptr, H2bf, N);
    agg_gather_kernel<64, true, true, true><<<(N + 31) / 32, blk, 0, stream>>>(
        H2bf, rowptr, perm_src, dinv, b2, H3bf, N);

    // ---- layer 3 ----
    agg_gather_kernel<64, false, false, false><<<(N + 31) / 32, blk, 0, stream>>>(
        H3bf, rowptr, perm_src, dinv, nullptr, T, N);
    gemm_mfma_kernel<64, 128, false, true, false><<<gRow, blk, 0, stream>>>(
        T, w3h, w3l, nullptr, b3, out, N);
}

// Round 6
// 229.617 us; speedup vs baseline: 1.8747x; 1.3370x over previous
//
#include <hip/hip_runtime.h>

// ---------------------------------------------------------------------------
// GCN 3-layer forward. CSR built by two-level LDS bucket sort (no per-edge
// global atomics). Gathers read bf16 H (f32 accum). GEMMs on MFMA bf16
// (hi/lo 3-product for f32 A, 2-product for bf16 A).
//
//   CSR: hist(dst>>8,196) -> scan -> chunked bucket scatter (packed
//        pk=(dst<<16)|src) -> per-bucket LDS sort -> rowptr/dinv/perm
//   L1: H1bf = x@W1 (3-prod)       ; AGG1bf = relu(Ahat(H1bf)+b1)
//   L2: H2bf = AGG1bf@W2 (2-prod)  ; H3bf   = relu(Ahat(H2bf)+b2)
//   L3: Tf   = Ahat(H3bf)          ; out    = Tf@W3+b3 (3-prod)
// MFMA 16x16x32 bf16; A[row=l&15][k=(l>>4)*8+j], B[k=(l>>4)*8+j][col=l&15],
// C/D col=l&15,row=(l>>4)*4+r (learn_hip m89).
// ---------------------------------------------------------------------------

#define DEV_INLINE __device__ __forceinline__

typedef unsigned int uint;
typedef unsigned short ushort;
typedef __attribute__((ext_vector_type(8))) short bf16x8;
typedef __attribute__((ext_vector_type(4))) float f32x4;

// ---- bf16 helpers ----
static DEV_INLINE uint f2bf_rne(float f) {
    uint u = __float_as_uint(f);
    return (u + 0x7FFFu + ((u >> 16) & 1u)) >> 16;
}
static DEV_INLINE uint pack2(float a, float b) { return f2bf_rne(a) | (f2bf_rne(b) << 16); }
static DEV_INLINE float bflo(uint u) { return __uint_as_float(u << 16); }
static DEV_INLINE float bfhi(uint u) { return __uint_as_float(u & 0xFFFF0000u); }

static DEV_INLINE void fma8(float4& a, float4& b, float n, const uint4& v) {
    a.x = fmaf(n, bflo(v.x), a.x); a.y = fmaf(n, bfhi(v.x), a.y);
    a.z = fmaf(n, bflo(v.y), a.z); a.w = fmaf(n, bfhi(v.y), a.w);
    b.x = fmaf(n, bflo(v.z), b.x); b.y = fmaf(n, bfhi(v.z), b.y);
    b.z = fmaf(n, bflo(v.w), b.z); b.w = fmaf(n, bfhi(v.w), b.w);
}

static DEV_INLINE void split8(const float4& x0, const float4& x1, bf16x8& ah, bf16x8& al) {
    float xs[8] = {x0.x, x0.y, x0.z, x0.w, x1.x, x1.y, x1.z, x1.w};
#pragma unroll
    for (int j = 0; j < 8; ++j) {
        uint u = __float_as_uint(xs[j]);
        ah[j] = (short)(u >> 16);
        float r = xs[j] - __uint_as_float(u & 0xFFFF0000u);
        al[j] = (short)(__float_as_uint(r) >> 16);
    }
}

// ------------------------- CSR: two-level bucket sort ------------------------
// bucket b = dst>>8 (NBK = ceil(N/256) = 196 for N=50000)

// coarse histogram via LDS privatization
__global__ __launch_bounds__(256) void hist_coarse_kernel(
    const int* __restrict__ dst, int* __restrict__ cnt196, int E, int NBK)
{
    __shared__ int h[256];
    if ((int)threadIdx.x < NBK) h[threadIdx.x] = 0;
    __syncthreads();
    for (int i = blockIdx.x * blockDim.x + threadIdx.x; i < E; i += gridDim.x * blockDim.x)
        atomicAdd(&h[dst[i] >> 8], 1);
    __syncthreads();
    if ((int)threadIdx.x < NBK) {
        int v = h[threadIdx.x];
        if (v) atomicAdd(&cnt196[threadIdx.x], v);
    }
}

// single-block scan of coarse counts -> base/cursor; also rowptr[N]=E
__global__ void scan_coarse_kernel(const int* __restrict__ cnt196, int* __restrict__ base196,
                                   int* __restrict__ cursor196, int* __restrict__ rowptr,
                                   int NBK, int N, int E)
{
    __shared__ int buf[256];
    const int tid = threadIdx.x;
    int v = (tid < NBK) ? cnt196[tid] : 0;
    buf[tid] = v;
    __syncthreads();
#pragma unroll
    for (int ofs = 1; ofs < 256; ofs <<= 1) {
        int t = (tid >= ofs) ? buf[tid - ofs] : 0;
        __syncthreads();
        buf[tid] += t;
        __syncthreads();
    }
    if (tid < NBK) {
        int b = buf[tid] - v;
        base196[tid] = b;
        cursor196[tid] = b;
    }
    if (tid == 0) rowptr[N] = E;
}

// chunked scatter into coarse buckets: each block claims per-bucket ranges
// (<=NBK coarse atomics) then writes packed edges densely.
__global__ __launch_bounds__(256) void scatter_coarse_kernel(
    const int* __restrict__ src, const int* __restrict__ dst,
    int* __restrict__ cursor196, uint* __restrict__ pkg, int E, int NBK)
{
    __shared__ int histL[256];
    __shared__ int baseL[256];
    const int tid = threadIdx.x;
    const int c0  = blockIdx.x * 2048;
    if (tid < NBK) histL[tid] = 0;
    __syncthreads();

    uint mypk[8];
    int  myn = 0;
#pragma unroll
    for (int k = 0; k < 8; ++k) {
        int idx = c0 + k * 256 + tid;
        if (idx < E) {
            uint pk = ((uint)dst[idx] << 16) | (uint)(src[idx] & 0xFFFF);
            mypk[myn++] = pk;
            atomicAdd(&histL[pk >> 24], 1);
        }
    }
    __syncthreads();
    if (tid < NBK) {
        int h = histL[tid];
        baseL[tid] = (h > 0) ? atomicAdd(&cursor196[tid], h) : 0;
        histL[tid] = 0;
    }
    __syncthreads();
    for (int k = 0; k < myn; ++k) {
        uint pk = mypk[k];
        int b = pk >> 24;
        int pos = baseL[b] + atomicAdd(&histL[b], 1);
        pkg[pos] = pk;
    }
}

// per-bucket LDS sort: one block per 256-node bucket -> rowptr, dinv, perm
__global__ __launch_bounds__(256) void build_fine_kernel(
    const uint* __restrict__ pkg, const int* __restrict__ cnt196,
    const int* __restrict__ base196, int* __restrict__ rowptr,
    float* __restrict__ dinv, ushort* __restrict__ perm, int N)
{
    __shared__ uint   pkL[8192];
    __shared__ ushort outS[8192];
    __shared__ int hist[256];
    __shared__ int buf[256];
    const int b   = blockIdx.x;
    const int tid = threadIdx.x;
    const int base = base196[b];
    int nE = cnt196[b];
    if (nE > 8192) nE = 8192;   // never triggers for this graph (max ~4.4k)

    hist[tid] = 0;
    __syncthreads();
    for (int i = tid; i < nE; i += 256) {
        uint pk = pkg[base + i];
        pkL[i] = pk;
        atomicAdd(&hist[(pk >> 16) & 255], 1);
    }
    __syncthreads();

    int cnt = hist[tid];
    buf[tid] = cnt;
    __syncthreads();
#pragma unroll
    for (int ofs = 1; ofs < 256; ofs <<= 1) {
        int t = (tid >= ofs) ? buf[tid - ofs] : 0;
        __syncthreads();
        buf[tid] += t;
        __syncthreads();
    }
    int excl = buf[tid] - cnt;
    int node = b * 256 + tid;
    if (node < N) {
        rowptr[node] = base + excl;
        dinv[node]   = rsqrtf((float)(cnt + 1));   // +1 self-loop
    }
    hist[tid] = excl;   // reuse as cursor
    __syncthreads();
    for (int i = tid; i < nE; i += 256) {
        uint pk = pkL[i];
        int d = (pk >> 16) & 255;
        int pos = atomicAdd(&hist[d], 1);
        outS[pos] = (ushort)(pk & 0xFFFFu);
    }
    __syncthreads();
    for (int i = tid; i < nE; i += 256) perm[base + i] = outS[i];
}

// ------------------------- W fragment prep (bf16 split) ---------------------

template<int K, int NOUT>
static DEV_INLINE void prep_one(const float* __restrict__ W,
                                ushort* __restrict__ Wh, ushort* __restrict__ Wl, int id) {
    constexpr int C = NOUT / 16;
    int lane = id & 63;
    int tc   = id >> 6;
    int c = tc % C, t = tc / C;
    int krow = t * 32 + (lane >> 4) * 8;
    int col  = c * 16 + (lane & 15);
#pragma unroll
    for (int j = 0; j < 8; ++j) {
        float w = W[(size_t)(krow + j) * NOUT + col];
        uint u = __float_as_uint(w);
        Wh[(size_t)id * 8 + j] = (ushort)(u >> 16);
        float r = w - __uint_as_float(u & 0xFFFF0000u);
        Wl[(size_t)id * 8 + j] = (ushort)(__float_as_uint(r) >> 16);
    }
}

__global__ void prep_wfrag_all_kernel(
    const float* __restrict__ W1, const float* __restrict__ W2, const float* __restrict__ W3,
    ushort* w1h, ushort* w1l, ushort* w2h, ushort* w2l, ushort* w3h, ushort* w3l)
{
    int id = blockIdx.x * 256 + threadIdx.x;
    if (id < 2048)       prep_one<128, 128>(W1, w1h, w1l, id);
    else if (id < 3072)  prep_one<128, 64>(W2, w2h, w2l, id - 2048);
    else if (id < 4096)  prep_one<64, 128>(W3, w3h, w3l, id - 3072);
}

// ------------------------------ MFMA GEMM -----------------------------------
// C[N,NOUT] = preact(A[N,K]) @ W
//   ABF:  A is packed bf16 (2-product: ah*bh + ah*bl)
//   else: A f32 hi/lo split (3-product)
//   PRE (f32 A only): relu(a + bias_k[k]);  POSTB: + bias_n[col]

template<int K, int NOUT, bool ABF, bool PRE, bool POSTB, bool OUTBF>
__global__ __launch_bounds__(256) void gemm_mfma_kernel(
    const void* __restrict__ A, const ushort* __restrict__ Whf, const ushort* __restrict__ Wlf,
    const float* __restrict__ bias_k, const float* __restrict__ bias_n,
    void* __restrict__ Cout, int N)
{
    constexpr int C  = NOUT / 16;
    constexpr int T  = K / 32;
    const int tid  = threadIdx.x;
    const int w    = tid >> 6;
    const int lane = tid & 63;
    const int row0 = blockIdx.x * 64 + w * 16;

    const int arow  = row0 + (lane & 15);
    const int arowc = (arow < N) ? arow : (N - 1);
    const int lq    = (lane >> 4);

    const bf16x8* WH = reinterpret_cast<const bf16x8*>(Whf);
    const bf16x8* WL = reinterpret_cast<const bf16x8*>(Wlf);

    f32x4 acc[C];
#pragma unroll
    for (int c = 0; c < C; ++c) acc[c] = (f32x4){0.f, 0.f, 0.f, 0.f};

#pragma unroll
    for (int t = 0; t < T; ++t) {
        bf16x8 ah, al;
        if (ABF) {
            const ushort* ap = (const ushort*)A + (size_t)arowc * K + t * 32 + lq * 8;
            ah = *reinterpret_cast<const bf16x8*>(ap);
        } else {
            const float* ap = (const float*)A + (size_t)arowc * K + t * 32 + lq * 8;
            float4 x0 = *reinterpret_cast<const float4*>(ap);
            float4 x1 = *reinterpret_cast<const float4*>(ap + 4);
            if (PRE) {
                const float* bp = bias_k + t * 32 + lq * 8;
                float4 b0 = *reinterpret_cast<const float4*>(bp);
                float4 b1 = *reinterpret_cast<const float4*>(bp + 4);
                x0.x = fmaxf(x0.x + b0.x, 0.f); x0.y = fmaxf(x0.y + b0.y, 0.f);
                x0.z = fmaxf(x0.z + b0.z, 0.f); x0.w = fmaxf(x0.w + b0.w, 0.f);
                x1.x = fmaxf(x1.x + b1.x, 0.f); x1.y = fmaxf(x1.y + b1.y, 0.f);
                x1.z = fmaxf(x1.z + b1.z, 0.f); x1.w = fmaxf(x1.w + b1.w, 0.f);
            }
            split8(x0, x1, ah, al);
        }
#pragma unroll
        for (int c = 0; c < C; ++c) {
            bf16x8 bh = WH[(t * C + c) * 64 + lane];
            bf16x8 bl = WL[(t * C + c) * 64 + lane];
            acc[c] = __builtin_amdgcn_mfma_f32_16x16x32_bf16(ah, bh, acc[c], 0, 0, 0);
            if (!ABF)
                acc[c] = __builtin_amdgcn_mfma_f32_16x16x32_bf16(al, bh, acc[c], 0, 0, 0);
            acc[c] = __builtin_amdgcn_mfma_f32_16x16x32_bf16(ah, bl, acc[c], 0, 0, 0);
        }
    }

    const int rbase = (lane >> 4) * 4;
    const int ccol  = (lane & 15);
#pragma unroll
    for (int c = 0; c < C; ++c) {
        int col = c * 16 + ccol;
        float pb = POSTB ? bias_n[col] : 0.f;
#pragma unroll
        for (int r = 0; r < 4; ++r) {
            int row = row0 + rbase + r;
            if (row < N) {
                float v = acc[c][r] + pb;
                if (OUTBF) ((ushort*)Cout)[(size_t)row * NOUT + col] = (ushort)f2bf_rne(v);
                else       ((float*)Cout)[(size_t)row * NOUT + col] = v;
            }
        }
    }
}

// ------------------------------ aggregation ---------------------------------

template<int F, bool BIAS, bool RELU, bool OUTBF>
__global__ __launch_bounds__(256) void agg_gather_kernel(
    const uint* __restrict__ H, const int* __restrict__ rowptr,
    const ushort* __restrict__ perm_src, const float* __restrict__ dinv,
    const float* __restrict__ bias, void* __restrict__ OUT, int N)
{
    constexpr int GROUP = F / 8;
    constexpr int FW    = F / 2;
    constexpr int NPB   = 256 / GROUP;
    const int lane = threadIdx.x % GROUP;
    const int g    = threadIdx.x / GROUP;
    const int node = blockIdx.x * NPB + g;
    if (node >= N) return;

    const int beg = rowptr[node];
    const int end = rowptr[node + 1];
    const float di = dinv[node];

    float4 aA = make_float4(0.f, 0.f, 0.f, 0.f), aB = aA;
    float4 bA = aA, bB = aA;
    {
        uint4 v = reinterpret_cast<const uint4*>(H + (size_t)node * FW)[lane];
        fma8(aA, aB, di * di, v);
    }

    int e = beg;
    for (; e + 3 < end; e += 4) {
        int s0 = perm_src[e];     int s1 = perm_src[e + 1];
        int s2 = perm_src[e + 2]; int s3 = perm_src[e + 3];
        float n0 = dinv[s0] * di, n1 = dinv[s1] * di;
        float n2 = dinv[s2] * di, n3 = dinv[s3] * di;
        uint4 v0 = reinterpret_cast<const uint4*>(H + (size_t)s0 * FW)[lane];
        uint4 v1 = reinterpret_cast<const uint4*>(H + (size_t)s1 * FW)[lane];
        uint4 v2 = reinterpret_cast<const uint4*>(H + (size_t)s2 * FW)[lane];
        uint4 v3 = reinterpret_cast<const uint4*>(H + (size_t)s3 * FW)[lane];
        fma8(aA, aB, n0, v0);
        fma8(bA, bB, n1, v1);
        fma8(aA, aB, n2, v2);
        fma8(bA, bB, n3, v3);
    }
    for (; e < end; ++e) {
        int s0 = perm_src[e];
        float n0 = dinv[s0] * di;
        uint4 v0 = reinterpret_cast<const uint4*>(H + (size_t)s0 * FW)[lane];
        fma8(aA, aB, n0, v0);
    }
    aA.x += bA.x; aA.y += bA.y; aA.z += bA.z; aA.w += bA.w;
    aB.x += bB.x; aB.y += bB.y; aB.z += bB.z; aB.w += bB.w;

    if (BIAS) {
        const float4* b4 = reinterpret_cast<const float4*>(bias);
        float4 c0 = b4[lane * 2], c1 = b4[lane * 2 + 1];
        aA.x += c0.x; aA.y += c0.y; aA.z += c0.z; aA.w += c0.w;
        aB.x += c1.x; aB.y += c1.y; aB.z += c1.z; aB.w += c1.w;
    }
    if (RELU) {
        aA.x = fmaxf(aA.x, 0.f); aA.y = fmaxf(aA.y, 0.f);
        aA.z = fmaxf(aA.z, 0.f); aA.w = fmaxf(aA.w, 0.f);
        aB.x = fmaxf(aB.x, 0.f); aB.y = fmaxf(aB.y, 0.f);
        aB.z = fmaxf(aB.z, 0.f); aB.w = fmaxf(aB.w, 0.f);
    }

    if (OUTBF) {
        uint4 u;
        u.x = pack2(aA.x, aA.y); u.y = pack2(aA.z, aA.w);
        u.z = pack2(aB.x, aB.y); u.w = pack2(aB.z, aB.w);
        reinterpret_cast<uint4*>((uint*)OUT + (size_t)node * FW)[lane] = u;
    } else {
        float4* O = reinterpret_cast<float4*>((float*)OUT + (size_t)node * F);
        O[lane * 2]     = aA;
        O[lane * 2 + 1] = aB;
    }
}

// ------------------------------- launcher -----------------------------------

static inline size_t align_up(size_t v, size_t a) { return (v + a - 1) / a * a; }

extern "C" void kernel_launch(void* const* d_in, const int* in_sizes, int n_in,
                              void* d_out, int out_size, void* d_ws, size_t ws_size,
                              hipStream_t stream) {
    const float* x  = (const float*)d_in[0];
    const int*   ei = (const int*)d_in[1];
    const float* W1 = (const float*)d_in[2];
    const float* b1 = (const float*)d_in[3];
    const float* W2 = (const float*)d_in[4];
    const float* b2 = (const float*)d_in[5];
    const float* W3 = (const float*)d_in[6];
    const float* b3 = (const float*)d_in[7];
    float* out = (float*)d_out;

    const int N = in_sizes[0] / 128;   // 50000
    const int E = in_sizes[1] / 2;     // 800000
    const int* src = ei;
    const int* dst = ei + E;
    const int NBK = (N + 255) / 256;   // 196 coarse buckets

    // workspace layout
    char* ws = (char*)d_ws;
    size_t off = 0;
    float* dinv   = (float*)(ws + off); off = align_up(off + (size_t)N * 4, 512);
    int*   rowptr = (int*)  (ws + off); off = align_up(off + (size_t)(N + 1) * 4, 512);
    int*   cnt196    = (int*)(ws + off); off = align_up(off + (size_t)NBK * 4, 512);
    int*   base196   = (int*)(ws + off); off = align_up(off + (size_t)NBK * 4, 512);
    int*   cursor196 = (int*)(ws + off); off = align_up(off + (size_t)NBK * 4, 512);
    ushort* perm_src = (ushort*)(ws + off); off = align_up(off + (size_t)E * 2, 512);
    uint*  pkg    = (uint*) (ws + off); off = align_up(off + (size_t)E * 4, 512);
    uint*  Hbf    = (uint*) (ws + off); off = align_up(off + (size_t)N * 128 * 2, 512);
    char*  Ashare = (char*) (ws + off); off = align_up(off + (size_t)N * 128 * 4, 512);
    ushort* w1h   = (ushort*)(ws + off); off = align_up(off + (size_t)128 * 128 * 2, 512);
    ushort* w1l   = (ushort*)(ws + off); off = align_up(off + (size_t)128 * 128 * 2, 512);
    ushort* w2h   = (ushort*)(ws + off); off = align_up(off + (size_t)128 * 64 * 2, 512);
    ushort* w2l   = (ushort*)(ws + off); off = align_up(off + (size_t)128 * 64 * 2, 512);
    ushort* w3h   = (ushort*)(ws + off); off = align_up(off + (size_t)64 * 128 * 2, 512);
    ushort* w3l   = (ushort*)(ws + off); off = align_up(off + (size_t)64 * 128 * 2, 512);
    (void)ws_size;

    uint* H1bf   = Hbf;                       // N*64 uints (bf16 x128)
    uint* H2bf   = Hbf;                       // N*32 (after H1 dead)
    uint* H3bf   = Hbf + (size_t)N * 32;      // N*32
    uint* AGG1bf = (uint*)Ashare;             // N*64 uints (bf16 x128)
    float* T     = (float*)Ashare;            // N*64 f32 (after AGG1bf dead)

    const int TPB = 256;
    dim3 blk(TPB);
    int gRow = (N + 63) / 64;

    // ---- W fragment prep (1 launch) ----
    prep_wfrag_all_kernel<<<16, blk, 0, stream>>>(W1, W2, W3, w1h, w1l, w2h, w2l, w3h, w3l);

    // ---- CSR build: two-level bucket sort, no per-edge global atomics ----
    hipMemsetAsync(cnt196, 0, (size_t)NBK * 4, stream);
    hist_coarse_kernel<<<392, blk, 0, stream>>>(dst, cnt196, E, NBK);
    scan_coarse_kernel<<<1, blk, 0, stream>>>(cnt196, base196, cursor196, rowptr, NBK, N, E);
    scatter_coarse_kernel<<<(E + 2047) / 2048, blk, 0, stream>>>(src, dst, cursor196, pkg, E, NBK);
    build_fine_kernel<<<NBK, blk, 0, stream>>>(pkg, cnt196, base196, rowptr, dinv, perm_src, N);

    // ---- layer 1: H1bf = x@W1 ; AGG1bf = relu(Ahat(H1bf)+b1) ----
    gemm_mfma_kernel<128, 128, false, false, false, true><<<gRow, blk, 0, stream>>>(
        x, w1h, w1l, nullptr, nullptr, H1bf, N);
    agg_gather_kernel<128, true, true, true><<<(N + 15) / 16, blk, 0, stream>>>(
        H1bf, rowptr, perm_src, dinv, b1, AGG1bf, N);

    // ---- layer 2: H2bf = AGG1bf@W2 ; H3bf = relu(Ahat(H2bf)+b2) ----
    gemm_mfma_kernel<128, 64, true, false, false, true><<<gRow, blk, 0, stream>>>(
        AGG1bf, w2h, w2l, nullptr, nullptr, H2bf, N);
    agg_gather_kernel<64, true, true, true><<<(N + 31) / 32, blk, 0, stream>>>(
        H2bf, rowptr, perm_src, dinv, b2, H3bf, N);

    // ---- layer 3: T = Ahat(H3bf) ; out = T@W3 + b3 ----
    agg_gather_kernel<64, false, false, false><<<(N + 31) / 32, blk, 0, stream>>>(
        H3bf, rowptr, perm_src, dinv, nullptr, T, N);
    gemm_mfma_kernel<64, 128, false, false, true, false><<<gRow, blk, 0, stream>>>(
        T, w3h, w3l, nullptr, b3, out, N);
}